// Round 7
// baseline (41.958 us; speedup 1.0000x reference)
//
#include <hip/hip_runtime.h>

#define BB 2
#define CC 8
#define DD 4
#define HH 256
#define WW 384
#define WV 4
#define WT (WW / WV)

typedef float f32x4 __attribute__((ext_vector_type(4)));

__global__ __launch_bounds__(256) void cqi3d_kernel(const float* __restrict__ x,
                                                    float* __restrict__ coords,
                                                    float* __restrict__ ymax) {
    const int tid = blockIdx.x * blockDim.x + threadIdx.x;
    const int nthreads = BB * CC * DD * HH * WT;
    if (tid >= nthreads) return;

    const int wt = tid % WT;
    int t = tid / WT;
    const int h = t % HH;
    t /= HH;
    const int d = t % DD;
    const int bc = t / DD;
    const int w0 = wt * WV;

    const int hm = h > 0 ? h - 1 : 0;
    const int hp = h < HH - 1 ? h + 1 : HH - 1;
    const int hr[3] = {hm, h, hp};
    const int dpl[3] = {d > 0 ? d - 1 : 0, d, d < DD - 1 ? d + 1 : DD - 1};
    const int wl = w0 > 0 ? w0 - 1 : 0;
    const int wr = (w0 + WV < WW) ? w0 + WV : WW - 1;

    const int plane = HH * WW;

    // register tile: rb[dplane][hrow][x], x = 0..5 covering w0-1 .. w0+4 (clamped)
    float rb[3][3][WV + 2];
#pragma unroll
    for (int i = 0; i < 3; ++i) {
#pragma unroll
        for (int j = 0; j < 3; ++j) {
            const float* row = x + ((bc * DD + dpl[i]) * HH + hr[j]) * WW;
            const f32x4 v4 = *reinterpret_cast<const f32x4*>(row + w0);
            rb[i][j][1] = v4.x;
            rb[i][j][2] = v4.y;
            rb[i][j][3] = v4.z;
            rb[i][j][4] = v4.w;
            rb[i][j][0] = row[wl];
            rb[i][j][5] = row[wr];
        }
    }

    // vertical (h) max per plane, then depth max -> 1D window maxes dm[6]
    float dm[WV + 2];
#pragma unroll
    for (int xx = 0; xx < WV + 2; ++xx) {
        const float m0 = fmaxf(fmaxf(rb[0][0][xx], rb[0][1][xx]), rb[0][2][xx]);
        const float m1 = fmaxf(fmaxf(rb[1][0][xx], rb[1][1][xx]), rb[1][2][xx]);
        const float m2 = fmaxf(fmaxf(rb[2][0][xx], rb[2][1][xx]), rb[2][2][xx]);
        dm[xx] = fmaxf(fmaxf(m0, m1), m2);
    }

    float yv[WV], o0[WV], o1[WV], o2[WV];
#pragma unroll
    for (int kk = 0; kk < WV; ++kk) {
        const int q = kk + 1;
        const float c = rb[1][1][q];

        // first-order gradients (depth flipped: b2 = f(d-1) - f(d+1))
        const float b0 = 0.5f * (rb[1][1][q + 1] - rb[1][1][q - 1]);
        const float b1 = 0.5f * (rb[1][2][q] - rb[1][0][q]);
        const float b2 = 0.5f * (rb[0][1][q] - rb[2][1][q]);

        // Hessian
        const float dxx = rb[1][1][q + 1] - 2.0f * c + rb[1][1][q - 1];
        const float dyy = rb[1][2][q] - 2.0f * c + rb[1][0][q];
        const float dss = rb[2][1][q] - 2.0f * c + rb[0][1][q];
        const float dxy = 0.25f * (rb[1][0][q - 1] - rb[1][0][q + 1] -
                                   rb[1][2][q - 1] + rb[1][2][q + 1]);
        const float dys = 0.25f * (-rb[0][0][q] + rb[0][2][q] +
                                   rb[2][0][q] - rb[2][2][q]);
        const float dxs = 0.25f * (-rb[0][1][q - 1] + rb[0][1][q + 1] +
                                   rb[2][1][q - 1] - rb[2][1][q + 1]);

        // NMS: center equals 3x3x3 window max
        const float mxv = fmaxf(fmaxf(dm[q - 1], dm[q]), dm[q + 1]);
        const bool nms = (c == mxv);

        // adjugate / det symmetric solve
        const float c00 = dyy * dss - dys * dys;
        const float c01 = dxs * dys - dxy * dss;
        const float c02 = dxy * dys - dxs * dyy;
        const float c11 = dxx * dss - dxs * dxs;
        const float c12 = dxy * dxs - dxx * dys;
        const float c22 = dxx * dyy - dxy * dxy;
        const float det = dxx * c00 + dxy * c01 + dxs * c02;

        const bool ok = nms && (det != 0.0f);
        // rcp(0)=inf -> u=inf -> mu>0.7 -> offsets zeroed; matches reference semantics
        const float invdet = __builtin_amdgcn_rcpf(det);
        const float u0 = (c00 * b0 + c01 * b1 + c02 * b2) * invdet;
        const float u1 = (c01 * b0 + c11 * b1 + c12 * b2) * invdet;
        const float u2 = (c02 * b0 + c12 * b1 + c22 * b2) * invdet;
        const float mu = fmaxf(fmaxf(fabsf(u0), fabsf(u1)), fabsf(u2));
        const bool keep = ok && (mu <= 0.7f);
        const float d0 = keep ? -u0 : 0.0f;
        const float d1 = keep ? -u1 : 0.0f;
        const float d2 = keep ? -u2 : 0.0f;

        const float dE = 0.5f * (b0 * d0 + b1 * d1 + b2 * d2);
        yv[kk] = c + dE + (ok ? 10.0f : 0.0f);
        o2[kk] = (float)d + d2;
        o0[kk] = (float)(w0 + kk) + d0;
        o1[kk] = (float)h + d1;
    }

    const int ybase = ((bc * DD + d) * HH + h) * WW + w0;
    const f32x4 yq = {yv[0], yv[1], yv[2], yv[3]};
    *reinterpret_cast<f32x4*>(ymax + ybase) = yq;

    const int cbase = ((bc * 3) * DD + d) * plane + h * WW + w0;
    const f32x4 q2 = {o2[0], o2[1], o2[2], o2[3]};
    const f32x4 q0 = {o0[0], o0[1], o0[2], o0[3]};
    const f32x4 q1 = {o1[0], o1[1], o1[2], o1[3]};
    *reinterpret_cast<f32x4*>(coords + cbase) = q2;                   // ch 0: d + d2
    *reinterpret_cast<f32x4*>(coords + cbase + DD * plane) = q0;      // ch 1: w + d0
    *reinterpret_cast<f32x4*>(coords + cbase + 2 * DD * plane) = q1;  // ch 2: h + d1
}

extern "C" void kernel_launch(void* const* d_in, const int* in_sizes, int n_in,
                              void* d_out, int out_size, void* d_ws, size_t ws_size,
                              hipStream_t stream) {
    const float* x = (const float*)d_in[0];
    float* out = (float*)d_out;
    float* coords = out;                                    // B*C*3*D*H*W
    float* ymax = out + (size_t)BB * CC * 3 * DD * HH * WW; // B*C*D*H*W

    const int nthreads = BB * CC * DD * HH * WT;
    const int block = 256;
    const int grid = (nthreads + block - 1) / block;
    cqi3d_kernel<<<grid, block, 0, stream>>>(x, coords, ymax);
}

// Round 8
// 28.013 us; speedup vs baseline: 1.4978x; 1.4978x over previous
//
#include <hip/hip_runtime.h>

#define BB 2
#define CC 8
#define DD 4
#define HH 256
#define WW 384
#define WV 4
#define WT (WW / WV)

typedef float f32x4 __attribute__((ext_vector_type(4)));

__global__ __launch_bounds__(256) void cqi3d_kernel(const float* __restrict__ x,
                                                    float* __restrict__ coords,
                                                    float* __restrict__ ymax) {
    const int tid = blockIdx.x * blockDim.x + threadIdx.x;
    const int nthreads = BB * CC * HH * WT;
    if (tid >= nthreads) return;

    const int wt = tid % WT;
    int t = tid / WT;
    const int h = t % HH;
    const int bc = t / HH;
    const int w0 = wt * WV;

    const int lane = threadIdx.x & 63;
    const bool isL = (lane == 0);
    const bool isR = (lane == 63);
    const bool wt0 = (wt == 0);
    const bool wtE = (wt == WT - 1);
    // one masked scalar load fixes both wave-boundary halos (2 active lanes/wave)
    const bool need = (isL && !wt0) || (isR && !wtE);
    const int off = isL ? (w0 - 1) : (w0 + WV);

    const int hm = h > 0 ? h - 1 : 0;
    const int hp = h < HH - 1 ? h + 1 : HH - 1;
    const int hr[3] = {hm, h, hp};

    const int plane = HH * WW;

    float P[DD][3][WV + 2];   // all indices compile-time after unroll
    float vm[DD][WV + 2];

#define LOAD_PLANE(p)  do {                                                   \
    _Pragma("unroll")                                                         \
    for (int j = 0; j < 3; ++j) {                                             \
        const float* row = x + ((bc * DD + (p)) * HH + hr[j]) * WW;           \
        const f32x4 v4 = *reinterpret_cast<const f32x4*>(row + w0);           \
        float eL = __shfl_up(v4.w, 1);                                        \
        float eR = __shfl_down(v4.x, 1);                                      \
        float eX = 0.0f;                                                      \
        if (need) eX = row[off];                                              \
        if (isL) eL = eX;                                                     \
        if (isR) eR = eX;                                                     \
        P[p][j][1] = v4.x; P[p][j][2] = v4.y;                                 \
        P[p][j][3] = v4.z; P[p][j][4] = v4.w;                                 \
        P[p][j][0] = wt0 ? v4.x : eL;                                         \
        P[p][j][5] = wtE ? v4.w : eR;                                         \
    }                                                                         \
    _Pragma("unroll")                                                         \
    for (int xx = 0; xx < WV + 2; ++xx)                                       \
        vm[p][xx] = fmaxf(fmaxf(P[p][0][xx], P[p][1][xx]), P[p][2][xx]);      \
} while (0)

#define COMPUTE_D(d, i0, i1, i2)  do {                                        \
    float dm[WV + 2];                                                         \
    _Pragma("unroll")                                                         \
    for (int xx = 0; xx < WV + 2; ++xx)                                       \
        dm[xx] = fmaxf(fmaxf(vm[i0][xx], vm[i1][xx]), vm[i2][xx]);            \
    float yv[WV], o0[WV], o1[WV], o2[WV];                                     \
    _Pragma("unroll")                                                         \
    for (int kk = 0; kk < WV; ++kk) {                                         \
        const int q = kk + 1;                                                 \
        const float c = P[i1][1][q];                                          \
        const float b0 = 0.5f * (P[i1][1][q + 1] - P[i1][1][q - 1]);          \
        const float b1 = 0.5f * (P[i1][2][q] - P[i1][0][q]);                  \
        const float b2 = 0.5f * (P[i0][1][q] - P[i2][1][q]);                  \
        const float dxx = P[i1][1][q + 1] - 2.0f * c + P[i1][1][q - 1];       \
        const float dyy = P[i1][2][q] - 2.0f * c + P[i1][0][q];               \
        const float dss = P[i2][1][q] - 2.0f * c + P[i0][1][q];               \
        const float dxy = 0.25f * (P[i1][0][q - 1] - P[i1][0][q + 1] -        \
                                   P[i1][2][q - 1] + P[i1][2][q + 1]);        \
        const float dys = 0.25f * (-P[i0][0][q] + P[i0][2][q] +               \
                                   P[i2][0][q] - P[i2][2][q]);                \
        const float dxs = 0.25f * (-P[i0][1][q - 1] + P[i0][1][q + 1] +       \
                                   P[i2][1][q - 1] - P[i2][1][q + 1]);        \
        const float mxv = fmaxf(fmaxf(dm[q - 1], dm[q]), dm[q + 1]);          \
        const bool nms = (c == mxv);                                          \
        const float c00 = dyy * dss - dys * dys;                              \
        const float c01 = dxs * dys - dxy * dss;                              \
        const float c02 = dxy * dys - dxs * dyy;                              \
        const float c11 = dxx * dss - dxs * dxs;                              \
        const float c12 = dxy * dxs - dxx * dys;                              \
        const float c22 = dxx * dyy - dxy * dxy;                              \
        const float det = dxx * c00 + dxy * c01 + dxs * c02;                  \
        const bool ok = nms && (det != 0.0f);                                 \
        const float invdet = __builtin_amdgcn_rcpf(det);                      \
        const float u0 = (c00 * b0 + c01 * b1 + c02 * b2) * invdet;           \
        const float u1 = (c01 * b0 + c11 * b1 + c12 * b2) * invdet;           \
        const float u2 = (c02 * b0 + c12 * b1 + c22 * b2) * invdet;           \
        const float mu = fmaxf(fmaxf(fabsf(u0), fabsf(u1)), fabsf(u2));       \
        const bool keep = ok && (mu <= 0.7f);                                 \
        const float d0 = keep ? -u0 : 0.0f;                                   \
        const float d1 = keep ? -u1 : 0.0f;                                   \
        const float d2 = keep ? -u2 : 0.0f;                                   \
        const float dE = 0.5f * (b0 * d0 + b1 * d1 + b2 * d2);                \
        yv[kk] = c + dE + (ok ? 10.0f : 0.0f);                                \
        o2[kk] = (float)(d) + d2;                                             \
        o0[kk] = (float)(w0 + kk) + d0;                                       \
        o1[kk] = (float)h + d1;                                               \
    }                                                                         \
    const int ybase = ((bc * DD + (d)) * HH + h) * WW + w0;                   \
    const f32x4 yq = {yv[0], yv[1], yv[2], yv[3]};                            \
    *reinterpret_cast<f32x4*>(ymax + ybase) = yq;                             \
    const int cbase = ((bc * 3) * DD + (d)) * plane + h * WW + w0;            \
    const f32x4 q2 = {o2[0], o2[1], o2[2], o2[3]};                            \
    const f32x4 q0 = {o0[0], o0[1], o0[2], o0[3]};                            \
    const f32x4 q1 = {o1[0], o1[1], o1[2], o1[3]};                            \
    *reinterpret_cast<f32x4*>(coords + cbase) = q2;                           \
    *reinterpret_cast<f32x4*>(coords + cbase + DD * plane) = q0;              \
    *reinterpret_cast<f32x4*>(coords + cbase + 2 * DD * plane) = q1;          \
} while (0)

    // rolling-d schedule: interleave plane loads with compute/stores
    LOAD_PLANE(0);
    LOAD_PLANE(1);
    COMPUTE_D(0, 0, 0, 1);   // d-1 clamps to 0
    LOAD_PLANE(2);
    COMPUTE_D(1, 0, 1, 2);
    LOAD_PLANE(3);
    COMPUTE_D(2, 1, 2, 3);
    COMPUTE_D(3, 2, 3, 3);   // d+1 clamps to 3
}

extern "C" void kernel_launch(void* const* d_in, const int* in_sizes, int n_in,
                              void* d_out, int out_size, void* d_ws, size_t ws_size,
                              hipStream_t stream) {
    const float* x = (const float*)d_in[0];
    float* out = (float*)d_out;
    float* coords = out;                                    // B*C*3*D*H*W
    float* ymax = out + (size_t)BB * CC * 3 * DD * HH * WW; // B*C*D*H*W

    const int nthreads = BB * CC * HH * WT;
    const int block = 256;
    const int grid = (nthreads + block - 1) / block;
    cqi3d_kernel<<<grid, block, 0, stream>>>(x, coords, ymax);
}

// Round 9
// 25.608 us; speedup vs baseline: 1.6384x; 1.0939x over previous
//
#include <hip/hip_runtime.h>

#define BB 2
#define CC 8
#define DD 4
#define HH 256
#define WW 384
#define WV 4
#define WT (WW / WV)
#define NBLK ((BB * CC * HH * WT) / 256)   // 1536 blocks
#define NXCD 8

typedef float f32x4 __attribute__((ext_vector_type(4)));

__global__ __launch_bounds__(256) void cqi3d_kernel(const float* __restrict__ x,
                                                    float* __restrict__ coords,
                                                    float* __restrict__ ymax) {
    // bijective XCD swizzle: blocks dispatch round-robin to XCDs (xcd = orig % 8);
    // remap so each XCD owns a CONTIGUOUS 192-block chunk -> h-neighbor rows share L2.
    const int orig = blockIdx.x;
    const int swz = (orig % NXCD) * (NBLK / NXCD) + orig / NXCD;
    const int tid = swz * 256 + threadIdx.x;

    const int wt = tid % WT;
    int t = tid / WT;
    const int h = t % HH;
    const int bc = t / HH;
    const int w0 = wt * WV;

    const int lane = threadIdx.x & 63;
    const bool isL = (lane == 0);
    const bool isR = (lane == 63);
    const bool wt0 = (wt == 0);
    const bool wtE = (wt == WT - 1);
    // one masked scalar load fixes both wave-boundary halos (2 active lanes/wave)
    const bool need = (isL && !wt0) || (isR && !wtE);
    const int off = isL ? (w0 - 1) : (w0 + WV);

    const int hm = h > 0 ? h - 1 : 0;
    const int hp = h < HH - 1 ? h + 1 : HH - 1;
    const int hr[3] = {hm, h, hp};

    const int plane = HH * WW;

    float P[DD][3][WV + 2];   // all indices compile-time after unroll
    float vm[DD][WV + 2];

#define LOAD_PLANE(p)  do {                                                   \
    _Pragma("unroll")                                                         \
    for (int j = 0; j < 3; ++j) {                                             \
        const float* row = x + ((bc * DD + (p)) * HH + hr[j]) * WW;           \
        const f32x4 v4 = *reinterpret_cast<const f32x4*>(row + w0);           \
        float eL = __shfl_up(v4.w, 1);                                        \
        float eR = __shfl_down(v4.x, 1);                                      \
        float eX = 0.0f;                                                      \
        if (need) eX = row[off];                                              \
        if (isL) eL = eX;                                                     \
        if (isR) eR = eX;                                                     \
        P[p][j][1] = v4.x; P[p][j][2] = v4.y;                                 \
        P[p][j][3] = v4.z; P[p][j][4] = v4.w;                                 \
        P[p][j][0] = wt0 ? v4.x : eL;                                         \
        P[p][j][5] = wtE ? v4.w : eR;                                         \
    }                                                                         \
    _Pragma("unroll")                                                         \
    for (int xx = 0; xx < WV + 2; ++xx)                                       \
        vm[p][xx] = fmaxf(fmaxf(P[p][0][xx], P[p][1][xx]), P[p][2][xx]);      \
} while (0)

#define COMPUTE_D(d, i0, i1, i2)  do {                                        \
    float dm[WV + 2];                                                         \
    _Pragma("unroll")                                                         \
    for (int xx = 0; xx < WV + 2; ++xx)                                       \
        dm[xx] = fmaxf(fmaxf(vm[i0][xx], vm[i1][xx]), vm[i2][xx]);            \
    float yv[WV], o0[WV], o1[WV], o2[WV];                                     \
    _Pragma("unroll")                                                         \
    for (int kk = 0; kk < WV; ++kk) {                                         \
        const int q = kk + 1;                                                 \
        const float c = P[i1][1][q];                                          \
        const float b0 = 0.5f * (P[i1][1][q + 1] - P[i1][1][q - 1]);          \
        const float b1 = 0.5f * (P[i1][2][q] - P[i1][0][q]);                  \
        const float b2 = 0.5f * (P[i0][1][q] - P[i2][1][q]);                  \
        const float dxx = P[i1][1][q + 1] - 2.0f * c + P[i1][1][q - 1];       \
        const float dyy = P[i1][2][q] - 2.0f * c + P[i1][0][q];               \
        const float dss = P[i2][1][q] - 2.0f * c + P[i0][1][q];               \
        const float dxy = 0.25f * (P[i1][0][q - 1] - P[i1][0][q + 1] -        \
                                   P[i1][2][q - 1] + P[i1][2][q + 1]);        \
        const float dys = 0.25f * (-P[i0][0][q] + P[i0][2][q] +               \
                                   P[i2][0][q] - P[i2][2][q]);                \
        const float dxs = 0.25f * (-P[i0][1][q - 1] + P[i0][1][q + 1] +       \
                                   P[i2][1][q - 1] - P[i2][1][q + 1]);        \
        const float mxv = fmaxf(fmaxf(dm[q - 1], dm[q]), dm[q + 1]);          \
        const bool nms = (c == mxv);                                          \
        const float c00 = dyy * dss - dys * dys;                              \
        const float c01 = dxs * dys - dxy * dss;                              \
        const float c02 = dxy * dys - dxs * dyy;                              \
        const float c11 = dxx * dss - dxs * dxs;                              \
        const float c12 = dxy * dxs - dxx * dys;                              \
        const float c22 = dxx * dyy - dxy * dxy;                              \
        const float det = dxx * c00 + dxy * c01 + dxs * c02;                  \
        const bool ok = nms && (det != 0.0f);                                 \
        const float invdet = __builtin_amdgcn_rcpf(det);                      \
        const float u0 = (c00 * b0 + c01 * b1 + c02 * b2) * invdet;           \
        const float u1 = (c01 * b0 + c11 * b1 + c12 * b2) * invdet;           \
        const float u2 = (c02 * b0 + c12 * b1 + c22 * b2) * invdet;           \
        const float mu = fmaxf(fmaxf(fabsf(u0), fabsf(u1)), fabsf(u2));       \
        const bool keep = ok && (mu <= 0.7f);                                 \
        const float d0 = keep ? -u0 : 0.0f;                                   \
        const float d1 = keep ? -u1 : 0.0f;                                   \
        const float d2 = keep ? -u2 : 0.0f;                                   \
        const float dE = 0.5f * (b0 * d0 + b1 * d1 + b2 * d2);                \
        yv[kk] = c + dE + (ok ? 10.0f : 0.0f);                                \
        o2[kk] = (float)(d) + d2;                                             \
        o0[kk] = (float)(w0 + kk) + d0;                                       \
        o1[kk] = (float)h + d1;                                               \
    }                                                                         \
    const int ybase = ((bc * DD + (d)) * HH + h) * WW + w0;                   \
    const f32x4 yq = {yv[0], yv[1], yv[2], yv[3]};                            \
    *reinterpret_cast<f32x4*>(ymax + ybase) = yq;                             \
    const int cbase = ((bc * 3) * DD + (d)) * plane + h * WW + w0;            \
    const f32x4 q2 = {o2[0], o2[1], o2[2], o2[3]};                            \
    const f32x4 q0 = {o0[0], o0[1], o0[2], o0[3]};                            \
    const f32x4 q1 = {o1[0], o1[1], o1[2], o1[3]};                            \
    *reinterpret_cast<f32x4*>(coords + cbase) = q2;                           \
    *reinterpret_cast<f32x4*>(coords + cbase + DD * plane) = q0;              \
    *reinterpret_cast<f32x4*>(coords + cbase + 2 * DD * plane) = q1;          \
} while (0)

    // rolling-d schedule: interleave plane loads with compute/stores
    LOAD_PLANE(0);
    LOAD_PLANE(1);
    COMPUTE_D(0, 0, 0, 1);   // d-1 clamps to 0
    LOAD_PLANE(2);
    COMPUTE_D(1, 0, 1, 2);
    LOAD_PLANE(3);
    COMPUTE_D(2, 1, 2, 3);
    COMPUTE_D(3, 2, 3, 3);   // d+1 clamps to 3
}

extern "C" void kernel_launch(void* const* d_in, const int* in_sizes, int n_in,
                              void* d_out, int out_size, void* d_ws, size_t ws_size,
                              hipStream_t stream) {
    const float* x = (const float*)d_in[0];
    float* out = (float*)d_out;
    float* coords = out;                                    // B*C*3*D*H*W
    float* ymax = out + (size_t)BB * CC * 3 * DD * HH * WW; // B*C*D*H*W

    cqi3d_kernel<<<NBLK, 256, 0, stream>>>(x, coords, ymax);
}

// Round 10
// 24.991 us; speedup vs baseline: 1.6789x; 1.0247x over previous
//
#include <hip/hip_runtime.h>

#define BB 2
#define CC 8
#define DD 4
#define HH 256
#define WW 384
#define WV 4
#define WT (WW / WV)
#define NBLK ((BB * CC * HH * WT) / 256)   // 1536 blocks
#define NXCD 8

typedef float f32x4 __attribute__((ext_vector_type(4)));

__global__ __launch_bounds__(256) void cqi3d_kernel(const float* __restrict__ x,
                                                    float* __restrict__ coords,
                                                    float* __restrict__ ymax) {
    // bijective XCD swizzle: blocks dispatch round-robin to XCDs (xcd = orig % 8);
    // remap so each XCD owns a CONTIGUOUS 192-block chunk -> h-neighbor rows share L2.
    const int orig = blockIdx.x;
    const int swz = (orig % NXCD) * (NBLK / NXCD) + orig / NXCD;
    const int tid = swz * 256 + threadIdx.x;

    const int wt = tid % WT;
    int t = tid / WT;
    const int h = t % HH;
    const int bc = t / HH;
    const int w0 = wt * WV;

    const int lane = threadIdx.x & 63;
    const bool isL = (lane == 0);
    const bool isR = (lane == 63);
    const bool wt0 = (wt == 0);
    const bool wtE = (wt == WT - 1);
    // one masked scalar load fixes both wave-boundary halos (2 active lanes/wave)
    const bool need = (isL && !wt0) || (isR && !wtE);
    const int off = isL ? (w0 - 1) : (w0 + WV);

    const int hm = h > 0 ? h - 1 : 0;
    const int hp = h < HH - 1 ? h + 1 : HH - 1;
    const int hr[3] = {hm, h, hp};

    const int plane = HH * WW;

    float P[DD][3][WV + 2];   // all indices compile-time after unroll
    float vm[DD][WV + 2];

#define LOAD_PLANE(p)  do {                                                   \
    _Pragma("unroll")                                                         \
    for (int j = 0; j < 3; ++j) {                                             \
        const float* row = x + ((bc * DD + (p)) * HH + hr[j]) * WW;           \
        const f32x4 v4 = *reinterpret_cast<const f32x4*>(row + w0);           \
        float eL = __shfl_up(v4.w, 1);                                        \
        float eR = __shfl_down(v4.x, 1);                                      \
        float eX = 0.0f;                                                      \
        if (need) eX = row[off];                                              \
        if (isL) eL = eX;                                                     \
        if (isR) eR = eX;                                                     \
        P[p][j][1] = v4.x; P[p][j][2] = v4.y;                                 \
        P[p][j][3] = v4.z; P[p][j][4] = v4.w;                                 \
        P[p][j][0] = wt0 ? v4.x : eL;                                         \
        P[p][j][5] = wtE ? v4.w : eR;                                         \
    }                                                                         \
    _Pragma("unroll")                                                         \
    for (int xx = 0; xx < WV + 2; ++xx)                                       \
        vm[p][xx] = fmaxf(fmaxf(P[p][0][xx], P[p][1][xx]), P[p][2][xx]);      \
} while (0)

#define COMPUTE_D(d, i0, i1, i2)  do {                                        \
    float dm[WV + 2];                                                         \
    _Pragma("unroll")                                                         \
    for (int xx = 0; xx < WV + 2; ++xx)                                       \
        dm[xx] = fmaxf(fmaxf(vm[i0][xx], vm[i1][xx]), vm[i2][xx]);            \
    float yv[WV], o0[WV], o1[WV], o2[WV];                                     \
    _Pragma("unroll")                                                         \
    for (int kk = 0; kk < WV; ++kk) {                                         \
        const int q = kk + 1;                                                 \
        const float c = P[i1][1][q];                                          \
        const float b0 = 0.5f * (P[i1][1][q + 1] - P[i1][1][q - 1]);          \
        const float b1 = 0.5f * (P[i1][2][q] - P[i1][0][q]);                  \
        const float b2 = 0.5f * (P[i0][1][q] - P[i2][1][q]);                  \
        const float dxx = P[i1][1][q + 1] - 2.0f * c + P[i1][1][q - 1];       \
        const float dyy = P[i1][2][q] - 2.0f * c + P[i1][0][q];               \
        const float dss = P[i2][1][q] - 2.0f * c + P[i0][1][q];               \
        const float dxy = 0.25f * (P[i1][0][q - 1] - P[i1][0][q + 1] -        \
                                   P[i1][2][q - 1] + P[i1][2][q + 1]);        \
        const float dys = 0.25f * (-P[i0][0][q] + P[i0][2][q] +               \
                                   P[i2][0][q] - P[i2][2][q]);                \
        const float dxs = 0.25f * (-P[i0][1][q - 1] + P[i0][1][q + 1] +       \
                                   P[i2][1][q - 1] - P[i2][1][q + 1]);        \
        const float mxv = fmaxf(fmaxf(dm[q - 1], dm[q]), dm[q + 1]);          \
        const bool nms = (c == mxv);                                          \
        const float c00 = dyy * dss - dys * dys;                              \
        const float c01 = dxs * dys - dxy * dss;                              \
        const float c02 = dxy * dys - dxs * dyy;                              \
        const float c11 = dxx * dss - dxs * dxs;                              \
        const float c12 = dxy * dxs - dxx * dys;                              \
        const float c22 = dxx * dyy - dxy * dxy;                              \
        const float det = dxx * c00 + dxy * c01 + dxs * c02;                  \
        const bool ok = nms && (det != 0.0f);                                 \
        const float invdet = __builtin_amdgcn_rcpf(det);                      \
        const float u0 = (c00 * b0 + c01 * b1 + c02 * b2) * invdet;           \
        const float u1 = (c01 * b0 + c11 * b1 + c12 * b2) * invdet;           \
        const float u2 = (c02 * b0 + c12 * b1 + c22 * b2) * invdet;           \
        const float mu = fmaxf(fmaxf(fabsf(u0), fabsf(u1)), fabsf(u2));       \
        const bool keep = ok && (mu <= 0.7f);                                 \
        const float d0 = keep ? -u0 : 0.0f;                                   \
        const float d1 = keep ? -u1 : 0.0f;                                   \
        const float d2 = keep ? -u2 : 0.0f;                                   \
        const float dE = 0.5f * (b0 * d0 + b1 * d1 + b2 * d2);                \
        yv[kk] = c + dE + (ok ? 10.0f : 0.0f);                                \
        o2[kk] = (float)(d) + d2;                                             \
        o0[kk] = (float)(w0 + kk) + d0;                                       \
        o1[kk] = (float)h + d1;                                               \
    }                                                                         \
    const int ybase = ((bc * DD + (d)) * HH + h) * WW + w0;                   \
    const f32x4 yq = {yv[0], yv[1], yv[2], yv[3]};                            \
    __builtin_nontemporal_store(yq, reinterpret_cast<f32x4*>(ymax + ybase));  \
    const int cbase = ((bc * 3) * DD + (d)) * plane + h * WW + w0;            \
    const f32x4 q2 = {o2[0], o2[1], o2[2], o2[3]};                            \
    const f32x4 q0 = {o0[0], o0[1], o0[2], o0[3]};                            \
    const f32x4 q1 = {o1[0], o1[1], o1[2], o1[3]};                            \
    __builtin_nontemporal_store(q2, reinterpret_cast<f32x4*>(coords + cbase));                  \
    __builtin_nontemporal_store(q0, reinterpret_cast<f32x4*>(coords + cbase + DD * plane));     \
    __builtin_nontemporal_store(q1, reinterpret_cast<f32x4*>(coords + cbase + 2 * DD * plane)); \
} while (0)

    // rolling-d schedule: interleave plane loads with compute/stores
    LOAD_PLANE(0);
    LOAD_PLANE(1);
    COMPUTE_D(0, 0, 0, 1);   // d-1 clamps to 0
    LOAD_PLANE(2);
    COMPUTE_D(1, 0, 1, 2);
    LOAD_PLANE(3);
    COMPUTE_D(2, 1, 2, 3);
    COMPUTE_D(3, 2, 3, 3);   // d+1 clamps to 3
}

extern "C" void kernel_launch(void* const* d_in, const int* in_sizes, int n_in,
                              void* d_out, int out_size, void* d_ws, size_t ws_size,
                              hipStream_t stream) {
    const float* x = (const float*)d_in[0];
    float* out = (float*)d_out;
    float* coords = out;                                    // B*C*3*D*H*W
    float* ymax = out + (size_t)BB * CC * 3 * DD * HH * WW; // B*C*D*H*W

    cqi3d_kernel<<<NBLK, 256, 0, stream>>>(x, coords, ymax);
}